// Round 6
// baseline (135.116 us; speedup 1.0000x reference)
//
#include <hip/hip_runtime.h>
#include <math.h>

#define BATCH 4
#define NPTS 8192
#define CH 512                 // candidates per LDS chunk (8 KB)
#define QPT 4                  // queries per thread (block covers 1024 queries)

// ---------------------------------------------------------------------------
// Kernel 1: warp xyz1 by flow1, pack as (-2x, -2y, -2z, |c|^2): scan key is
// d' = |c|^2 - 2<c,q> (3 FMAs, same per-query ordering as |c-q|^2; identical
// expansion form to the reference's selection). Coords recovered exactly in
// the epilogue as x = -0.5 * c.x (power-of-two scale).
// ---------------------------------------------------------------------------
__global__ __launch_bounds__(256) void prep_kernel(
    const float* __restrict__ xyz1, const float* __restrict__ flow1,
    float4* __restrict__ cand)
{
    int t = blockIdx.x * 256 + threadIdx.x;        // BATCH*NPTS threads
    int b = t >> 13;
    int n = t & (NPTS - 1);
    const float* x = xyz1 + b * 3 * NPTS + n;
    const float* f = flow1 + b * 3 * NPTS + n;
    float wx = x[0]        + f[0];
    float wy = x[NPTS]     + f[NPTS];
    float wz = x[2 * NPTS] + f[2 * NPTS];
    float nrm = fmaf(wx, wx, fmaf(wy, wy, wz * wz));
    cand[t] = make_float4(-2.0f * wx, -2.0f * wy, -2.0f * wz, nrm);
}

// ---------------------------------------------------------------------------
// Kernel 2: LDS-broadcast partial 3-NN scan, register-tiled Q=4.
// Block = 256 threads; thread t owns queries {j, j+256, j+512, j+768} of the
// block's 1024-query window, scanning ONE candidate segment staged chunk-wise
// into LDS. One ds_read_b128 (broadcast, conflict-free) now feeds 4 key
// evaluations + 4 sorted-insert updates (~56 VALU) -> LDS pressure /4 vs R5,
// VALU issue is the binding resource. All top-3 state in NAMED registers.
// Strict '<' + ascending k preserves lowest-index-wins tie-break.
// ---------------------------------------------------------------------------
#define UPD(QX, QY, QZ, E0, E1, E2, I0, I1, I2) do {                  \
    float d = fmaf(c.x, QX, fmaf(c.y, QY, fmaf(c.z, QZ, c.w)));       \
    bool c0 = d < E0, c1 = d < E1, c2 = d < E2;                       \
    float n1 = __builtin_amdgcn_fmed3f(E0, E1, d);                    \
    float n2 = __builtin_amdgcn_fmed3f(E1, E2, d);                    \
    I2 = c1 ? I1 : (c2 ? kk : I2);                                    \
    I1 = c0 ? I0 : (c1 ? kk : I1);                                    \
    I0 = c0 ? kk : I0;                                                \
    E0 = fminf(E0, d); E1 = n1; E2 = n2;                              \
} while (0)

__global__ __launch_bounds__(256, 4) void scan_kernel(
    const float* __restrict__ xyz2, const float4* __restrict__ cand,
    float* __restrict__ pd, int* __restrict__ pi, int lgsegs)
{
    __shared__ float4 sc[CH];

    int SEGS   = 1 << lgsegs;
    int SEGLEN = NPTS >> lgsegs;
    int t   = (int)threadIdx.x;
    int seg = blockIdx.x & (SEGS - 1);
    int qt  = (blockIdx.x >> lgsegs) & 7;          // NPTS/1024 = 8 query tiles
    int b   = blockIdx.x >> (lgsegs + 3);
    int j   = qt * 1024 + t;

    const float* qp = xyz2 + b * 3 * NPTS + j;
    float q0x = qp[0],   q0y = qp[NPTS],       q0z = qp[2 * NPTS];
    float q1x = qp[256], q1y = qp[NPTS + 256], q1z = qp[2 * NPTS + 256];
    float q2x = qp[512], q2y = qp[NPTS + 512], q2z = qp[2 * NPTS + 512];
    float q3x = qp[768], q3y = qp[NPTS + 768], q3z = qp[2 * NPTS + 768];

    const float4* src = cand + b * NPTS + seg * SEGLEN;

    float e00 = 3.4e38f, e01 = 3.4e38f, e02 = 3.4e38f;
    float e10 = 3.4e38f, e11 = 3.4e38f, e12 = 3.4e38f;
    float e20 = 3.4e38f, e21 = 3.4e38f, e22 = 3.4e38f;
    float e30 = 3.4e38f, e31 = 3.4e38f, e32 = 3.4e38f;
    int k00 = 0, k01 = 0, k02 = 0;
    int k10 = 0, k11 = 0, k12 = 0;
    int k20 = 0, k21 = 0, k22 = 0;
    int k30 = 0, k31 = 0, k32 = 0;

    for (int cb = 0; cb < SEGLEN; cb += CH) {
        // stage 512 candidates (2 coalesced float4 loads/thread)
        float4 r0 = src[cb + t];
        float4 r1 = src[cb + t + 256];
        __syncthreads();                 // previous chunk fully consumed
        sc[t]       = r0;
        sc[t + 256] = r1;
        __syncthreads();

        #pragma unroll 4
        for (int k = 0; k < CH; ++k) {
            float4 c = sc[k];            // same addr across lanes: broadcast
            int kk = cb + k;
            UPD(q0x, q0y, q0z, e00, e01, e02, k00, k01, k02);
            UPD(q1x, q1y, q1z, e10, e11, e12, k10, k11, k12);
            UPD(q2x, q2y, q2z, e20, e21, e22, k20, k21, k22);
            UPD(q3x, q3y, q3z, e30, e31, e32, k30, k31, k32);
        }
    }

    int off = seg * SEGLEN;
    size_t base = ((size_t)(b * SEGS + seg) * 3) * NPTS + j;   // [b][seg][slot][N]
    pd[base]            = e00;  pi[base]            = k00 + off;
    pd[base + NPTS]     = e01;  pi[base + NPTS]     = k01 + off;
    pd[base + 2 * NPTS] = e02;  pi[base + 2 * NPTS] = k02 + off;
    pd[base + 256]            = e10;  pi[base + 256]            = k10 + off;
    pd[base + NPTS + 256]     = e11;  pi[base + NPTS + 256]     = k11 + off;
    pd[base + 2 * NPTS + 256] = e12;  pi[base + 2 * NPTS + 256] = k12 + off;
    pd[base + 512]            = e20;  pi[base + 512]            = k20 + off;
    pd[base + NPTS + 512]     = e21;  pi[base + NPTS + 512]     = k21 + off;
    pd[base + 2 * NPTS + 512] = e22;  pi[base + 2 * NPTS + 512] = k22 + off;
    pd[base + 768]            = e30;  pi[base + 768]            = k30 + off;
    pd[base + NPTS + 768]     = e31;  pi[base + NPTS + 768]     = k31 + off;
    pd[base + 2 * NPTS + 768] = e32;  pi[base + 2 * NPTS + 768] = k32 + off;
}

// ---------------------------------------------------------------------------
// Kernel 3: merge SEGS partial top-3s per query (ascending segment order ->
// lowest global index wins ties), then inverse-distance-weight epilogue.
// ---------------------------------------------------------------------------
__device__ __forceinline__ void insert3(float d, int idx,
    float& e0, float& e1, float& e2, int& i0, int& i1, int& i2)
{
    if (d < e2) {
        bool c1 = d < e1, c0 = d < e0;
        e2 = c1 ? e1 : d;   i2 = c1 ? i1 : idx;
        e1 = c0 ? e0 : (c1 ? d : e1);
        i1 = c0 ? i0 : (c1 ? idx : i1);
        e0 = c0 ? d : e0;   i0 = c0 ? idx : i0;
    }
}

__global__ __launch_bounds__(256) void merge_kernel(
    const float* __restrict__ xyz2, const float* __restrict__ flow1,
    const float4* __restrict__ cand,
    const float* __restrict__ pd, const int* __restrict__ pi,
    float* __restrict__ out, int lgsegs)
{
    int g = blockIdx.x * 256 + (int)threadIdx.x;   // BATCH*NPTS threads
    int b = g >> 13;
    int j = g & (NPTS - 1);
    int SEGS = 1 << lgsegs;

    float m0 = 3.4e38f, m1 = 3.4e38f, m2 = 3.4e38f;
    int   n0 = 0, n1 = 0, n2 = 0;
    for (int s = 0; s < SEGS; ++s) {
        size_t base = ((size_t)(b * SEGS + s) * 3) * NPTS + j;
        insert3(pd[base],            pi[base],            m0, m1, m2, n0, n1, n2);
        insert3(pd[base + NPTS],     pi[base + NPTS],     m0, m1, m2, n0, n1, n2);
        insert3(pd[base + 2 * NPTS], pi[base + 2 * NPTS], m0, m1, m2, n0, n1, n2);
    }

    const float* qp = xyz2 + b * 3 * NPTS + j;
    float px = qp[0], py = qp[NPTS], pz = qp[2 * NPTS];

    const float4* cbb = cand + b * NPTS;
    const float*  fb  = flow1 + b * 3 * NPTS;

    float wsum = 0.f, f2x = 0.f, f2y = 0.f, f2z = 0.f;
    int idxs[3] = { n0, n1, n2 };
    #pragma unroll
    for (int k = 0; k < 3; ++k) {
        int id = idxs[k];
        float4 c = cbb[id];
        float cx = -0.5f * c.x, cy = -0.5f * c.y, cz = -0.5f * c.z;  // exact
        float dx = cx - px, dy = cy - py, dz = cz - pz;
        float dist = sqrtf(fmaf(dx, dx, fmaf(dy, dy, dz * dz)));
        dist = fmaxf(dist, 1e-10f);
        float w = 1.0f / dist;
        wsum += w;
        f2x = fmaf(w, fb[id],            f2x);
        f2y = fmaf(w, fb[NPTS + id],     f2y);
        f2z = fmaf(w, fb[2 * NPTS + id], f2z);
    }
    float r = 1.0f / wsum;
    float* ob = out + b * 3 * NPTS;
    ob[j]            = px - f2x * r;
    ob[NPTS + j]     = py - f2y * r;
    ob[2 * NPTS + j] = pz - f2z * r;
}

// ---------------------------------------------------------------------------
// Launcher. Workspace (adaptive SEGS by ws_size):
//   cand: 512 KB; pd+pi: 768KB*SEGS.  SEGS=16: 12.8MB ... SEGS=2: 2.0MB.
// Grid: BATCH * (NPTS/1024 query tiles) * SEGS blocks.
// ---------------------------------------------------------------------------
extern "C" void kernel_launch(void* const* d_in, const int* in_sizes, int n_in,
                              void* d_out, int out_size, void* d_ws, size_t ws_size,
                              hipStream_t stream)
{
    const float* xyz1  = (const float*)d_in[0];
    const float* xyz2  = (const float*)d_in[1];
    const float* flow1 = (const float*)d_in[2];
    float* out = (float*)d_out;

    const size_t CAND_BYTES = (size_t)BATCH * NPTS * sizeof(float4);   // 512 KB
    int lgsegs = 1;
    for (int lg = 4; lg >= 1; --lg) {
        size_t need = CAND_BYTES + (size_t)BATCH * NPTS * (1 << lg) * 3 * 8;
        if (need <= ws_size) { lgsegs = lg; break; }
    }
    int SEGS = 1 << lgsegs;
    size_t pd_bytes = (size_t)BATCH * NPTS * SEGS * 3 * sizeof(float);

    float4* cand = (float4*)d_ws;
    float*  pd   = (float*)((char*)d_ws + CAND_BYTES);
    int*    pi   = (int*)((char*)d_ws + CAND_BYTES + pd_bytes);

    prep_kernel <<<BATCH * NPTS / 256, 256, 0, stream>>>(xyz1, flow1, cand);
    scan_kernel <<<BATCH * 8 * SEGS,   256, 0, stream>>>(xyz2, cand, pd, pi, lgsegs);
    merge_kernel<<<BATCH * NPTS / 256, 256, 0, stream>>>(xyz2, flow1, cand, pd, pi, out, lgsegs);
}

// Round 7
// 128.708 us; speedup vs baseline: 1.0498x; 1.0498x over previous
//
#include <hip/hip_runtime.h>
#include <math.h>

#define BATCH 4
#define NPTS 8192

// ---------------------------------------------------------------------------
// Kernel 1: warp xyz1 by flow1, pack as (-2x, -2y, -2z, |c|^2): scan key is
// d' = |c|^2 - 2<c,q> (3 FMAs, same per-query ordering as |c-q|^2; identical
// expansion form to the reference's selection). Coords recovered exactly in
// the epilogue as x = -0.5 * c.x (power-of-two scale).
// ---------------------------------------------------------------------------
__global__ __launch_bounds__(256) void prep_kernel(
    const float* __restrict__ xyz1, const float* __restrict__ flow1,
    float4* __restrict__ cand)
{
    int t = blockIdx.x * 256 + threadIdx.x;        // BATCH*NPTS threads
    int b = t >> 13;
    int n = t & (NPTS - 1);
    const float* x = xyz1 + b * 3 * NPTS + n;
    const float* f = flow1 + b * 3 * NPTS + n;
    float wx = x[0]        + f[0];
    float wy = x[NPTS]     + f[NPTS];
    float wz = x[2 * NPTS] + f[2 * NPTS];
    float nrm = fmaf(wx, wx, fmaf(wy, wy, wz * wz));
    cand[t] = make_float4(-2.0f * wx, -2.0f * wy, -2.0f * wz, nrm);
}

// ---------------------------------------------------------------------------
// Kernel 2: scalar-load partial 3-NN scan. NO LDS.
// Block = 256 threads = 256 queries (one per thread); block scans ONE segment.
// The candidate address is wave-uniform (blockIdx + loop counter only), so
// hipcc scalarizes the loads to s_load_dwordx4 (proven in R0: VGPR_Count=8).
// Candidate traffic rides the SCALAR pipe / K-cache (512 KB stream, L2-hot);
// the VALU runs only the ~15-op key+insert per candidate. Wave count =
// 32768 queries * SEGS / 64; SEGS=16 -> 2048 blocks = 8 blocks/CU.
// Strict '<' + ascending k preserves lowest-index-wins tie-break.
// ---------------------------------------------------------------------------
__global__ __launch_bounds__(256, 8) void scan_kernel(
    const float* __restrict__ xyz2, const float4* __restrict__ cand,
    float* __restrict__ pd, unsigned short* __restrict__ pi, int lgsegs)
{
    int SEGS   = 1 << lgsegs;
    int SEGLEN = NPTS >> lgsegs;
    int t   = (int)threadIdx.x;
    int seg = blockIdx.x & (SEGS - 1);
    int qt  = (blockIdx.x >> lgsegs) & 31;         // NPTS/256 = 32 query tiles
    int b   = blockIdx.x >> (lgsegs + 5);
    int j   = qt * 256 + t;

    const float* qp = xyz2 + b * 3 * NPTS + j;
    float qx = qp[0], qy = qp[NPTS], qz = qp[2 * NPTS];

    const float4* src = cand + b * NPTS + seg * SEGLEN;   // fully uniform base

    float e0 = 3.4e38f, e1 = 3.4e38f, e2 = 3.4e38f;
    int   i0 = 0, i1 = 0, i2 = 0;

    #pragma unroll 8
    for (int k = 0; k < SEGLEN; ++k) {
        float4 c = src[k];               // uniform addr -> s_load (SGPRs)
        float d = fmaf(c.x, qx, fmaf(c.y, qy, fmaf(c.z, qz, c.w)));
        bool c0 = d < e0, c1 = d < e1, c2 = d < e2;
        float n1 = __builtin_amdgcn_fmed3f(e0, e1, d);   // 2nd smallest
        float n2 = __builtin_amdgcn_fmed3f(e1, e2, d);   // 3rd smallest
        i2 = c1 ? i1 : (c2 ? k : i2);
        i1 = c0 ? i0 : (c1 ? k : i1);
        i0 = c0 ? k : i0;
        e0 = fminf(e0, d); e1 = n1; e2 = n2;
    }

    size_t base = ((size_t)(b * SEGS + seg) * 3) * NPTS + j;   // [b][seg][slot][N]
    pd[base]            = e0;  pi[base]            = (unsigned short)i0;
    pd[base + NPTS]     = e1;  pi[base + NPTS]     = (unsigned short)i1;
    pd[base + 2 * NPTS] = e2;  pi[base + 2 * NPTS] = (unsigned short)i2;
}

// ---------------------------------------------------------------------------
// Kernel 3: merge SEGS partial top-3s per query (ascending segment order ->
// lowest global index wins ties; stored indices are segment-local, globalized
// here), then inverse-distance-weight epilogue.
// ---------------------------------------------------------------------------
__device__ __forceinline__ void insert3(float d, int idx,
    float& e0, float& e1, float& e2, int& i0, int& i1, int& i2)
{
    if (d < e2) {
        bool c1 = d < e1, c0 = d < e0;
        e2 = c1 ? e1 : d;   i2 = c1 ? i1 : idx;
        e1 = c0 ? e0 : (c1 ? d : e1);
        i1 = c0 ? i0 : (c1 ? idx : i1);
        e0 = c0 ? d : e0;   i0 = c0 ? idx : i0;
    }
}

__global__ __launch_bounds__(256) void merge_kernel(
    const float* __restrict__ xyz2, const float* __restrict__ flow1,
    const float4* __restrict__ cand,
    const float* __restrict__ pd, const unsigned short* __restrict__ pi,
    float* __restrict__ out, int lgsegs)
{
    int g = blockIdx.x * 256 + (int)threadIdx.x;   // BATCH*NPTS threads
    int b = g >> 13;
    int j = g & (NPTS - 1);
    int SEGS   = 1 << lgsegs;
    int SEGLEN = NPTS >> lgsegs;

    float m0 = 3.4e38f, m1 = 3.4e38f, m2 = 3.4e38f;
    int   n0 = 0, n1 = 0, n2 = 0;
    for (int s = 0; s < SEGS; ++s) {
        size_t base = ((size_t)(b * SEGS + s) * 3) * NPTS + j;
        int off = s * SEGLEN;
        insert3(pd[base],            pi[base] + off,            m0, m1, m2, n0, n1, n2);
        insert3(pd[base + NPTS],     pi[base + NPTS] + off,     m0, m1, m2, n0, n1, n2);
        insert3(pd[base + 2 * NPTS], pi[base + 2 * NPTS] + off, m0, m1, m2, n0, n1, n2);
    }

    const float* qp = xyz2 + b * 3 * NPTS + j;
    float px = qp[0], py = qp[NPTS], pz = qp[2 * NPTS];

    const float4* cbb = cand + b * NPTS;
    const float*  fb  = flow1 + b * 3 * NPTS;

    float wsum = 0.f, f2x = 0.f, f2y = 0.f, f2z = 0.f;
    int idxs[3] = { n0, n1, n2 };
    #pragma unroll
    for (int k = 0; k < 3; ++k) {
        int id = idxs[k];
        float4 c = cbb[id];
        float cx = -0.5f * c.x, cy = -0.5f * c.y, cz = -0.5f * c.z;  // exact
        float dx = cx - px, dy = cy - py, dz = cz - pz;
        float dist = sqrtf(fmaf(dx, dx, fmaf(dy, dy, dz * dz)));
        dist = fmaxf(dist, 1e-10f);
        float w = 1.0f / dist;
        wsum += w;
        f2x = fmaf(w, fb[id],            f2x);
        f2y = fmaf(w, fb[NPTS + id],     f2y);
        f2z = fmaf(w, fb[2 * NPTS + id], f2z);
    }
    float r = 1.0f / wsum;
    float* ob = out + b * 3 * NPTS;
    ob[j]            = px - f2x * r;
    ob[NPTS + j]     = py - f2y * r;
    ob[2 * NPTS + j] = pz - f2z * r;
}

// ---------------------------------------------------------------------------
// Launcher. Workspace (adaptive SEGS):
//   cand 512 KB; pd = 384KB*SEGS (f32); pi = 192KB*SEGS (u16, idx<8192).
//   SEGS=16 -> 9.95 MB; SEGS=8 -> 5.2 MB; ... SEGS=2 -> 1.7 MB.
// Grid: BATCH * 32 query tiles * SEGS.
// ---------------------------------------------------------------------------
extern "C" void kernel_launch(void* const* d_in, const int* in_sizes, int n_in,
                              void* d_out, int out_size, void* d_ws, size_t ws_size,
                              hipStream_t stream)
{
    const float* xyz1  = (const float*)d_in[0];
    const float* xyz2  = (const float*)d_in[1];
    const float* flow1 = (const float*)d_in[2];
    float* out = (float*)d_out;

    const size_t CAND_BYTES = (size_t)BATCH * NPTS * sizeof(float4);   // 512 KB
    int lgsegs = 1;
    for (int lg = 4; lg >= 1; --lg) {
        size_t need = CAND_BYTES + (size_t)BATCH * NPTS * (1 << lg) * 3 * (4 + 2);
        if (need <= ws_size) { lgsegs = lg; break; }
    }
    int SEGS = 1 << lgsegs;
    size_t pd_bytes = (size_t)BATCH * NPTS * SEGS * 3 * sizeof(float);

    float4*         cand = (float4*)d_ws;
    float*          pd   = (float*)((char*)d_ws + CAND_BYTES);
    unsigned short* pi   = (unsigned short*)((char*)d_ws + CAND_BYTES + pd_bytes);

    prep_kernel <<<BATCH * NPTS / 256, 256, 0, stream>>>(xyz1, flow1, cand);
    scan_kernel <<<BATCH * 32 * SEGS,  256, 0, stream>>>(xyz2, cand, pd, pi, lgsegs);
    merge_kernel<<<BATCH * NPTS / 256, 256, 0, stream>>>(xyz2, flow1, cand, pd, pi, out, lgsegs);
}